// Round 15
// baseline (102.280 us; speedup 1.0000x reference)
//
#include <hip/hip_runtime.h>
#include <hip/hip_bf16.h>
#include <stdint.h>

// x[L=512][N=64][D=512] f32, upfold[O=512][N=64][D=512] f32
//   S[l,o,n] = sum_d x[l,n,d]*up[o,n,d] / sqrt(512);  W = sigmoid(S)-0.5
//   out[l,n,d] = sum_o W[l,o,n] * up[o,n,d]   (f32)
//
// Round 15 = round-14 with kPrepUp4 (512-thread prep, wider LDS reads):
//   kPrepUp4: 512 blocks x 512 thr (16 waves/CU vs r14's 8):
//     A: up tile 128o x 256d -> ub bf16 + LDS (swizzled), 8 passes
//     B: LDS -> ut bf16 via u32 d-PAIR reads (32 ds_read_b32/thread vs
//        r14's 128 ds_read_u16), 4 passes, 256B-segment writes
//     C: 64 x-rows -> xb bf16, 8 passes (streaming)
//   kGemmP<1>/<2>: round-8 schedule, unchanged (measured at memory floor).

typedef __attribute__((ext_vector_type(8))) short short8;   // 8 bf16
typedef __attribute__((ext_vector_type(4))) float f32x4;

__device__ __forceinline__ uint16_t f2bf(float f) {
    uint32_t u = __builtin_bit_cast(uint32_t, f);
    uint32_t r = u + 0x7FFFu + ((u >> 16) & 1u);   // RNE
    return (uint16_t)(r >> 16);
}
__device__ __forceinline__ uint32_t cvt2(float a, float b) {
    return (uint32_t)f2bf(a) | ((uint32_t)f2bf(b) << 16);
}

// ---------------- kPrepUp4: ub + ut + xb from up, x ---------------------------
// 512 blocks (64 n x 4 og x 2 dg) x 512 thr. LDS tile 128o x 256d bf16,
// row stride 272 u16, chunk-XOR swizzle ch^((o>>3)&15).
__global__ __launch_bounds__(512) void kPrepUp4(const float* __restrict__ up,
                                                const float* __restrict__ x,
                                                uint16_t* __restrict__ ub,
                                                uint16_t* __restrict__ ut,
                                                uint16_t* __restrict__ xb) {
    __shared__ uint16_t tl[128 * 272];    // 68 KB
    int bid = blockIdx.x;
    int n   = bid >> 3;
    int sub = bid & 7;
    int o0 = (sub >> 1) * 128;
    int d0 = (sub & 1) * 256;
    int tid = threadIdx.x;

    // Phase A: up -> ub + LDS. 8 passes x 16 rows; 32 lanes x 8 f32 (1KB read).
    int rp = tid >> 5;                    // row-in-pass 0..15
    int ch = tid & 31;                    // 8-elem d-chunk 0..31
    #pragma unroll
    for (int p = 0; p < 8; ++p) {
        int o = p * 16 + rp;              // local o 0..127
        const float* src = up + ((size_t)(o0 + o) * 64 + n) * 512 + d0 + ch * 8;
        float4 v0 = *reinterpret_cast<const float4*>(src);
        float4 v1 = *reinterpret_cast<const float4*>(src + 4);
        uint32_t pk[4] = {cvt2(v0.x, v0.y), cvt2(v0.z, v0.w),
                          cvt2(v1.x, v1.y), cvt2(v1.z, v1.w)};
        *reinterpret_cast<uint4*>(ub + ((size_t)n * 512 + o0 + o) * 512 + d0 + ch * 8) =
            *reinterpret_cast<const uint4*>(pk);
        int chs = ch ^ ((o >> 3) & 15);   // swizzled chunk for LDS
        *reinterpret_cast<uint4*>(&tl[o * 272 + chs * 8]) =
            *reinterpret_cast<const uint4*>(pk);
    }
    __syncthreads();

    // Phase B: LDS -> ut. 4 passes x 32 d-pairs; each thread: 8 u32 reads,
    // produces ut rows d and d+1 (16B each; 16 lanes -> 256B segments).
    int oc = (tid & 15) * 8;              // o-chunk base 0..120
    int dp = tid >> 4;                    // d-pair-in-pass 0..31
    #pragma unroll
    for (int q = 0; q < 4; ++q) {
        int d = (q * 32 + dp) * 2;        // even local d 0..254
        uint16_t g0[8], g1[8];
        #pragma unroll
        for (int j = 0; j < 8; ++j) {
            int o = oc + j;
            int chs = (d >> 3) ^ ((o >> 3) & 15);
            uint32_t w = *reinterpret_cast<const uint32_t*>(
                &tl[o * 272 + chs * 8 + (d & 7)]);
            g0[j] = (uint16_t)(w & 0xFFFFu);
            g1[j] = (uint16_t)(w >> 16);
        }
        uint16_t* dst = ut + ((size_t)n * 512 + d0 + d) * 512 + o0 + oc;
        *reinterpret_cast<uint4*>(dst)       = *reinterpret_cast<const uint4*>(g0);
        *reinterpret_cast<uint4*>(dst + 512) = *reinterpret_cast<const uint4*>(g1);
    }

    // Phase C: x -> xb, 64 l-rows for this (n, sub). No barrier needed.
    // 8 passes x 8 rows; 64 lanes x 8 f32 per row (2KB read, 1KB write).
    int rl = tid >> 6;                    // row-in-pass 0..7
    int cx = tid & 63;                    // 8-elem d-chunk 0..63
    #pragma unroll
    for (int p = 0; p < 8; ++p) {
        int l = sub * 64 + p * 8 + rl;
        const float* src = x + ((size_t)l * 64 + n) * 512 + cx * 8;
        float4 v0 = *reinterpret_cast<const float4*>(src);
        float4 v1 = *reinterpret_cast<const float4*>(src + 4);
        uint32_t pk[4] = {cvt2(v0.x, v0.y), cvt2(v0.z, v0.w),
                          cvt2(v1.x, v1.y), cvt2(v1.z, v1.w)};
        *reinterpret_cast<uint4*>(xb + ((size_t)n * 512 + l) * 512 + cx * 8) =
            *reinterpret_cast<const uint4*>(pk);
    }
}

// ---------------- pipelined 256^2 GEMM: C = A . B^T, panels [n][512][512] -----
// MODE 1: sigmoid epilogue -> W bf16 [n][l][o].  MODE 2: f32 -> out[l][n][d].
// BK=32, 16 K-steps, 4-buffer LDS rotation, counted vmcnt(8). (round-8 exact)
template<int MODE>
__global__ __launch_bounds__(512) void kGemmP(const uint16_t* __restrict__ A,
                                              const uint16_t* __restrict__ B,
                                              void* __restrict__ outp) {
    __shared__ __align__(16) uint16_t As[4][8192];   // 256 rows x 32 k = 16KB/buf
    __shared__ __align__(16) uint16_t Bs[4][8192];
    int bid = blockIdx.x;                     // XCD n-grouping: xcd=bid&7 owns 8 n's
    int n  = (bid & 7) * 8 + (bid >> 5);
    int t  = (bid >> 3) & 3;
    int l0 = (t >> 1) << 8, c0 = (t & 1) << 8;
    int tid = threadIdx.x, lane = tid & 63, wid = tid >> 6;
    int wr = wid >> 2, wc = wid & 3;          // per-wave out 128x64

    const char* An = (const char*)(A + (size_t)n * 262144);
    const char* Bn = (const char*)(B + (size_t)n * 262144);

    int s1 = tid, s2 = tid + 512;
    int r1 = s1 >> 2, r2 = s2 >> 2;
    int cg1 = (s1 & 3) ^ ((r1 >> 1) & 3);
    int cg2 = (s2 & 3) ^ ((r2 >> 1) & 3);
    const char* gA1 = An + (size_t)(l0 + r1) * 1024 + cg1 * 16;
    const char* gA2 = An + (size_t)(l0 + r2) * 1024 + cg2 * 16;
    const char* gB1 = Bn + (size_t)(c0 + r1) * 1024 + cg1 * 16;
    const char* gB2 = Bn + (size_t)(c0 + r2) * 1024 + cg2 * 16;

    f32x4 acc[8][4];
    #pragma unroll
    for (int m = 0; m < 8; ++m)
        #pragma unroll
        for (int nf = 0; nf < 4; ++nf) acc[m][nf] = (f32x4)(0.f);

    auto STAGE = [&](int buf, int kt) {
        int ko = kt * 64;                     // 32 k * 2B
        uint16_t* lA = &As[buf][wid * 512];   // wave-uniform base + lane*16 HW
        uint16_t* lB = &Bs[buf][wid * 512];
        __builtin_amdgcn_global_load_lds(
            (const __attribute__((address_space(1))) uint32_t*)(gA1 + ko),
            (__attribute__((address_space(3))) uint32_t*)(lA), 16, 0, 0);
        __builtin_amdgcn_global_load_lds(
            (const __attribute__((address_space(1))) uint32_t*)(gA2 + ko),
            (__attribute__((address_space(3))) uint32_t*)(lA + 4096), 16, 0, 0);
        __builtin_amdgcn_global_load_lds(
            (const __attribute__((address_space(1))) uint32_t*)(gB1 + ko),
            (__attribute__((address_space(3))) uint32_t*)(lB), 16, 0, 0);
        __builtin_amdgcn_global_load_lds(
            (const __attribute__((address_space(1))) uint32_t*)(gB2 + ko),
            (__attribute__((address_space(3))) uint32_t*)(lB + 4096), 16, 0, 0);
    };

    STAGE(0, 0);
    STAGE(1, 1);
    STAGE(2, 2);
    asm volatile("s_waitcnt vmcnt(8)" ::: "memory");
    __builtin_amdgcn_s_barrier();
    __builtin_amdgcn_sched_barrier(0);

    int g = lane >> 4;                        // k-chunk 0..3 (8 bf16 each)
    #pragma unroll
    for (int kt = 0; kt < 16; ++kt) {
        const int cur = kt & 3;
        if (kt < 13) STAGE((kt + 3) & 3, kt + 3);   // issue 3 tiles ahead
        const char* Ac = (const char*)As[cur];
        const char* Bc = (const char*)Bs[cur];
        short8 a[8], bb[4];
        #pragma unroll
        for (int nf = 0; nf < 4; ++nf) {
            int row = wc * 64 + nf * 16 + (lane & 15);
            int off = row * 64 + ((g ^ ((row >> 1) & 3)) << 4);
            bb[nf] = *reinterpret_cast<const short8*>(Bc + off);
        }
        #pragma unroll
        for (int m = 0; m < 8; ++m) {
            int row = wr * 128 + m * 16 + (lane & 15);
            int off = row * 64 + ((g ^ ((row >> 1) & 3)) << 4);
            a[m] = *reinterpret_cast<const short8*>(Ac + off);
        }
        #pragma unroll
        for (int m = 0; m < 8; ++m)
            #pragma unroll
            for (int nf = 0; nf < 4; ++nf)
                acc[m][nf] = __builtin_amdgcn_mfma_f32_16x16x32_bf16(
                    a[m], bb[nf], acc[m][nf], 0, 0, 0);
        if (kt < 13) {
            asm volatile("s_waitcnt vmcnt(8)" ::: "memory");
            __builtin_amdgcn_s_barrier();
            __builtin_amdgcn_sched_barrier(0);
        } else if (kt == 13) {
            asm volatile("s_waitcnt vmcnt(4)" ::: "memory");
            __builtin_amdgcn_s_barrier();
            __builtin_amdgcn_sched_barrier(0);
        } else if (kt == 14) {
            asm volatile("s_waitcnt vmcnt(0)" ::: "memory");
            __builtin_amdgcn_s_barrier();
            __builtin_amdgcn_sched_barrier(0);
        }
    }

    if constexpr (MODE == 1) {
        uint16_t* Wn = (uint16_t*)outp + (size_t)n * 262144;
        const float scale = 0.044194173824159216f;   // 1/sqrt(512)
        #pragma unroll
        for (int m = 0; m < 8; ++m) {
            int lrow0 = l0 + wr * 128 + m * 16 + ((lane >> 4) << 2);
            #pragma unroll
            for (int nf = 0; nf < 4; ++nf) {
                int ocol = c0 + wc * 64 + nf * 16 + (lane & 15);
                #pragma unroll
                for (int r = 0; r < 4; ++r) {
                    float aff = acc[m][nf][r] * scale;
                    float w = 1.f / (1.f + __expf(-aff)) - 0.5f;
                    Wn[(size_t)(lrow0 + r) * 512 + ocol] = f2bf(w);
                }
            }
        }
    } else {
        float* On = (float*)outp;
        #pragma unroll
        for (int m = 0; m < 8; ++m) {
            int lrow0 = l0 + wr * 128 + m * 16 + ((lane >> 4) << 2);
            #pragma unroll
            for (int nf = 0; nf < 4; ++nf) {
                int dcol = c0 + wc * 64 + nf * 16 + (lane & 15);
                #pragma unroll
                for (int r = 0; r < 4; ++r)
                    On[((size_t)(lrow0 + r) * 64 + n) * 512 + dcol] = acc[m][nf][r];
            }
        }
    }
}

// ---------------- naive fallback ---------------------------------------------
__global__ __launch_bounds__(256) void kNaive(const float* __restrict__ x,
                                              const float* __restrict__ up,
                                              float* __restrict__ out) {
    __shared__ float xr[512];
    __shared__ float w[512];
    int b = blockIdx.x;
    int l = b >> 6, n = b & 63;
    int tid = threadIdx.x;
    const float* xrow = x + ((size_t)l * 64 + n) * 512;
    xr[tid] = xrow[tid];
    xr[tid + 256] = xrow[tid + 256];
    __syncthreads();
    const float scale = 0.044194173824159216f;
    #pragma unroll
    for (int oo = 0; oo < 2; ++oo) {
        int o = tid + oo * 256;
        const float* ur = up + ((size_t)o * 64 + n) * 512;
        float s = 0.f;
        for (int dd = 0; dd < 512; ++dd) s += xr[dd] * ur[dd];
        w[o] = 1.f / (1.f + __expf(-s * scale)) - 0.5f;
    }
    __syncthreads();
    #pragma unroll
    for (int dd = 0; dd < 2; ++dd) {
        int d = tid + dd * 256;
        float f = 0.f;
        for (int o = 0; o < 512; ++o)
            f += w[o] * up[((size_t)o * 64 + n) * 512 + d];
        out[((size_t)l * 64 + n) * 512 + d] = f;
    }
}

extern "C" void kernel_launch(void* const* d_in, const int* in_sizes, int n_in,
                              void* d_out, int out_size, void* d_ws, size_t ws_size,
                              hipStream_t stream) {
    const float* x  = (const float*)d_in[0];
    const float* up = (const float*)d_in[1];
    float* out = (float*)d_out;

    const size_t MB32 = (size_t)64 * 512 * 512 * 2;   // one bf16 panel set
    if (ws_size >= 4 * MB32) {
        uint16_t* XB = (uint16_t*)d_ws;
        uint16_t* UB = XB + 16777216;
        uint16_t* UT = UB + 16777216;
        uint16_t* W  = UT + 16777216;
        kPrepUp4<<<512, 512, 0, stream>>>(up, x, UB, UT, XB);
        kGemmP<1><<<256, 512, 0, stream>>>(XB, UB, W);
        kGemmP<2><<<256, 512, 0, stream>>>(W, UT, out);
    } else {
        kNaive<<<512 * 64, 256, 0, stream>>>(x, up, out);
    }
}

// Round 16
// 99.703 us; speedup vs baseline: 1.0258x; 1.0258x over previous
//
#include <hip/hip_runtime.h>
#include <hip/hip_bf16.h>
#include <stdint.h>

// x[L=512][N=64][D=512] f32, upfold[O=512][N=64][D=512] f32
//   S[l,o,n] = sum_d x[l,n,d]*up[o,n,d] / sqrt(512);  W = sigmoid(S)-0.5
//   out[l,n,d] = sum_o W[l,o,n] * up[o,n,d]   (f32)
//
// Round 16 = round-14 exact (best measured: 99.8 us). Pipeline:
//   kPrepUp3 (512 blk x 256 thr): A: up tile -> ub bf16 + LDS (swizzled);
//     B: LDS -> ut bf16 (256B writes); C: x -> xb bf16 (streaming).
//     64.4 us for 368 MB = 5.7 TB/s (~90% of streaming ceiling).
//   kGemmP<1>: W = sig(xb.ub^T/sqrt(D))-0.5   (~17 us, memory floor)
//   kGemmP<2>: out = W.ut^T                    (~17 us, memory floor)
// GEMM: 256^2, 8 waves, BK=32, 4 LDS bufs, counted vmcnt(8), XCD n-grouping.
// Total ~= 635 MB pipeline traffic at 6.3 TB/s ~= 101 us floor -> at roofline.

typedef __attribute__((ext_vector_type(8))) short short8;   // 8 bf16
typedef __attribute__((ext_vector_type(4))) float f32x4;

__device__ __forceinline__ uint16_t f2bf(float f) {
    uint32_t u = __builtin_bit_cast(uint32_t, f);
    uint32_t r = u + 0x7FFFu + ((u >> 16) & 1u);   // RNE
    return (uint16_t)(r >> 16);
}
__device__ __forceinline__ uint32_t cvt2(float a, float b) {
    return (uint32_t)f2bf(a) | ((uint32_t)f2bf(b) << 16);
}

// ---------------- kPrepUp3: ub + ut + xb from up, x ---------------------------
// 512 blocks (64 n x 4 og x 2 dg) x 256 thr. LDS tile 128o x 256d bf16,
// row stride 272, chunk-XOR swizzle ch^((o>>3)&15).
__global__ __launch_bounds__(256) void kPrepUp3(const float* __restrict__ up,
                                                const float* __restrict__ x,
                                                uint16_t* __restrict__ ub,
                                                uint16_t* __restrict__ ut,
                                                uint16_t* __restrict__ xb) {
    __shared__ uint16_t tl[128 * 272];    // 68 KB
    int bid = blockIdx.x;
    int n   = bid >> 3;
    int sub = bid & 7;
    int o0 = (sub >> 1) * 128;
    int d0 = (sub & 1) * 256;
    int tid = threadIdx.x;

    // Phase A: up -> ub + LDS. 16 passes x 8 rows; 32 lanes x 8 f32 (1KB read).
    int rp = tid >> 5;                    // row-in-pass 0..7
    int ch = tid & 31;                    // 8-elem d-chunk 0..31
    #pragma unroll
    for (int p = 0; p < 16; ++p) {
        int o = p * 8 + rp;               // local o 0..127
        const float* src = up + ((size_t)(o0 + o) * 64 + n) * 512 + d0 + ch * 8;
        float4 v0 = *reinterpret_cast<const float4*>(src);
        float4 v1 = *reinterpret_cast<const float4*>(src + 4);
        uint32_t pk[4] = {cvt2(v0.x, v0.y), cvt2(v0.z, v0.w),
                          cvt2(v1.x, v1.y), cvt2(v1.z, v1.w)};
        *reinterpret_cast<uint4*>(ub + ((size_t)n * 512 + o0 + o) * 512 + d0 + ch * 8) =
            *reinterpret_cast<const uint4*>(pk);
        int chs = ch ^ ((o >> 3) & 15);   // swizzled chunk for LDS
        *reinterpret_cast<uint4*>(&tl[o * 272 + chs * 8]) =
            *reinterpret_cast<const uint4*>(pk);
    }
    __syncthreads();

    // Phase B: LDS -> ut rows. 16 passes x 16 d-rows; 16 lanes x 16B (256B).
    int oc = (tid & 15) * 8;              // o-chunk base
    int dr = tid >> 4;                    // d row-in-pass 0..15
    #pragma unroll
    for (int q = 0; q < 16; ++q) {
        int d = q * 16 + dr;              // local d 0..255
        uint16_t g[8];
        #pragma unroll
        for (int j = 0; j < 8; ++j) {
            int o = oc + j;
            int chs = (d >> 3) ^ ((o >> 3) & 15);
            g[j] = tl[o * 272 + chs * 8 + (d & 7)];
        }
        *reinterpret_cast<uint4*>(ut + ((size_t)n * 512 + d0 + d) * 512 + o0 + oc) =
            *reinterpret_cast<const uint4*>(g);
    }

    // Phase C: x -> xb, 64 l-rows for this (n, sub). No LDS, no barrier.
    int rl = tid >> 6;                    // row-in-pass 0..3
    int cx = tid & 63;                    // 8-elem d-chunk 0..63
    #pragma unroll
    for (int p = 0; p < 16; ++p) {
        int l = sub * 64 + p * 4 + rl;
        const float* src = x + ((size_t)l * 64 + n) * 512 + cx * 8;
        float4 v0 = *reinterpret_cast<const float4*>(src);
        float4 v1 = *reinterpret_cast<const float4*>(src + 4);
        uint32_t pk[4] = {cvt2(v0.x, v0.y), cvt2(v0.z, v0.w),
                          cvt2(v1.x, v1.y), cvt2(v1.z, v1.w)};
        *reinterpret_cast<uint4*>(xb + ((size_t)n * 512 + l) * 512 + cx * 8) =
            *reinterpret_cast<const uint4*>(pk);
    }
}

// ---------------- pipelined 256^2 GEMM: C = A . B^T, panels [n][512][512] -----
// MODE 1: sigmoid epilogue -> W bf16 [n][l][o].  MODE 2: f32 -> out[l][n][d].
// BK=32, 16 K-steps, 4-buffer LDS rotation, counted vmcnt(8). (round-8 exact)
template<int MODE>
__global__ __launch_bounds__(512) void kGemmP(const uint16_t* __restrict__ A,
                                              const uint16_t* __restrict__ B,
                                              void* __restrict__ outp) {
    __shared__ __align__(16) uint16_t As[4][8192];   // 256 rows x 32 k = 16KB/buf
    __shared__ __align__(16) uint16_t Bs[4][8192];
    int bid = blockIdx.x;                     // XCD n-grouping: xcd=bid&7 owns 8 n's
    int n  = (bid & 7) * 8 + (bid >> 5);
    int t  = (bid >> 3) & 3;
    int l0 = (t >> 1) << 8, c0 = (t & 1) << 8;
    int tid = threadIdx.x, lane = tid & 63, wid = tid >> 6;
    int wr = wid >> 2, wc = wid & 3;          // per-wave out 128x64

    const char* An = (const char*)(A + (size_t)n * 262144);
    const char* Bn = (const char*)(B + (size_t)n * 262144);

    int s1 = tid, s2 = tid + 512;
    int r1 = s1 >> 2, r2 = s2 >> 2;
    int cg1 = (s1 & 3) ^ ((r1 >> 1) & 3);
    int cg2 = (s2 & 3) ^ ((r2 >> 1) & 3);
    const char* gA1 = An + (size_t)(l0 + r1) * 1024 + cg1 * 16;
    const char* gA2 = An + (size_t)(l0 + r2) * 1024 + cg2 * 16;
    const char* gB1 = Bn + (size_t)(c0 + r1) * 1024 + cg1 * 16;
    const char* gB2 = Bn + (size_t)(c0 + r2) * 1024 + cg2 * 16;

    f32x4 acc[8][4];
    #pragma unroll
    for (int m = 0; m < 8; ++m)
        #pragma unroll
        for (int nf = 0; nf < 4; ++nf) acc[m][nf] = (f32x4)(0.f);

    auto STAGE = [&](int buf, int kt) {
        int ko = kt * 64;                     // 32 k * 2B
        uint16_t* lA = &As[buf][wid * 512];   // wave-uniform base + lane*16 HW
        uint16_t* lB = &Bs[buf][wid * 512];
        __builtin_amdgcn_global_load_lds(
            (const __attribute__((address_space(1))) uint32_t*)(gA1 + ko),
            (__attribute__((address_space(3))) uint32_t*)(lA), 16, 0, 0);
        __builtin_amdgcn_global_load_lds(
            (const __attribute__((address_space(1))) uint32_t*)(gA2 + ko),
            (__attribute__((address_space(3))) uint32_t*)(lA + 4096), 16, 0, 0);
        __builtin_amdgcn_global_load_lds(
            (const __attribute__((address_space(1))) uint32_t*)(gB1 + ko),
            (__attribute__((address_space(3))) uint32_t*)(lB), 16, 0, 0);
        __builtin_amdgcn_global_load_lds(
            (const __attribute__((address_space(1))) uint32_t*)(gB2 + ko),
            (__attribute__((address_space(3))) uint32_t*)(lB + 4096), 16, 0, 0);
    };

    STAGE(0, 0);
    STAGE(1, 1);
    STAGE(2, 2);
    asm volatile("s_waitcnt vmcnt(8)" ::: "memory");
    __builtin_amdgcn_s_barrier();
    __builtin_amdgcn_sched_barrier(0);

    int g = lane >> 4;                        // k-chunk 0..3 (8 bf16 each)
    #pragma unroll
    for (int kt = 0; kt < 16; ++kt) {
        const int cur = kt & 3;
        if (kt < 13) STAGE((kt + 3) & 3, kt + 3);   // issue 3 tiles ahead
        const char* Ac = (const char*)As[cur];
        const char* Bc = (const char*)Bs[cur];
        short8 a[8], bb[4];
        #pragma unroll
        for (int nf = 0; nf < 4; ++nf) {
            int row = wc * 64 + nf * 16 + (lane & 15);
            int off = row * 64 + ((g ^ ((row >> 1) & 3)) << 4);
            bb[nf] = *reinterpret_cast<const short8*>(Bc + off);
        }
        #pragma unroll
        for (int m = 0; m < 8; ++m) {
            int row = wr * 128 + m * 16 + (lane & 15);
            int off = row * 64 + ((g ^ ((row >> 1) & 3)) << 4);
            a[m] = *reinterpret_cast<const short8*>(Ac + off);
        }
        #pragma unroll
        for (int m = 0; m < 8; ++m)
            #pragma unroll
            for (int nf = 0; nf < 4; ++nf)
                acc[m][nf] = __builtin_amdgcn_mfma_f32_16x16x32_bf16(
                    a[m], bb[nf], acc[m][nf], 0, 0, 0);
        if (kt < 13) {
            asm volatile("s_waitcnt vmcnt(8)" ::: "memory");
            __builtin_amdgcn_s_barrier();
            __builtin_amdgcn_sched_barrier(0);
        } else if (kt == 13) {
            asm volatile("s_waitcnt vmcnt(4)" ::: "memory");
            __builtin_amdgcn_s_barrier();
            __builtin_amdgcn_sched_barrier(0);
        } else if (kt == 14) {
            asm volatile("s_waitcnt vmcnt(0)" ::: "memory");
            __builtin_amdgcn_s_barrier();
            __builtin_amdgcn_sched_barrier(0);
        }
    }

    if constexpr (MODE == 1) {
        uint16_t* Wn = (uint16_t*)outp + (size_t)n * 262144;
        const float scale = 0.044194173824159216f;   // 1/sqrt(512)
        #pragma unroll
        for (int m = 0; m < 8; ++m) {
            int lrow0 = l0 + wr * 128 + m * 16 + ((lane >> 4) << 2);
            #pragma unroll
            for (int nf = 0; nf < 4; ++nf) {
                int ocol = c0 + wc * 64 + nf * 16 + (lane & 15);
                #pragma unroll
                for (int r = 0; r < 4; ++r) {
                    float aff = acc[m][nf][r] * scale;
                    float w = 1.f / (1.f + __expf(-aff)) - 0.5f;
                    Wn[(size_t)(lrow0 + r) * 512 + ocol] = f2bf(w);
                }
            }
        }
    } else {
        float* On = (float*)outp;
        #pragma unroll
        for (int m = 0; m < 8; ++m) {
            int lrow0 = l0 + wr * 128 + m * 16 + ((lane >> 4) << 2);
            #pragma unroll
            for (int nf = 0; nf < 4; ++nf) {
                int dcol = c0 + wc * 64 + nf * 16 + (lane & 15);
                #pragma unroll
                for (int r = 0; r < 4; ++r)
                    On[((size_t)(lrow0 + r) * 64 + n) * 512 + dcol] = acc[m][nf][r];
            }
        }
    }
}

// ---------------- naive fallback ---------------------------------------------
__global__ __launch_bounds__(256) void kNaive(const float* __restrict__ x,
                                              const float* __restrict__ up,
                                              float* __restrict__ out) {
    __shared__ float xr[512];
    __shared__ float w[512];
    int b = blockIdx.x;
    int l = b >> 6, n = b & 63;
    int tid = threadIdx.x;
    const float* xrow = x + ((size_t)l * 64 + n) * 512;
    xr[tid] = xrow[tid];
    xr[tid + 256] = xrow[tid + 256];
    __syncthreads();
    const float scale = 0.044194173824159216f;
    #pragma unroll
    for (int oo = 0; oo < 2; ++oo) {
        int o = tid + oo * 256;
        const float* ur = up + ((size_t)o * 64 + n) * 512;
        float s = 0.f;
        for (int dd = 0; dd < 512; ++dd) s += xr[dd] * ur[dd];
        w[o] = 1.f / (1.f + __expf(-s * scale)) - 0.5f;
    }
    __syncthreads();
    #pragma unroll
    for (int dd = 0; dd < 2; ++dd) {
        int d = tid + dd * 256;
        float f = 0.f;
        for (int o = 0; o < 512; ++o)
            f += w[o] * up[((size_t)o * 64 + n) * 512 + d];
        out[((size_t)l * 64 + n) * 512 + d] = f;
    }
}

extern "C" void kernel_launch(void* const* d_in, const int* in_sizes, int n_in,
                              void* d_out, int out_size, void* d_ws, size_t ws_size,
                              hipStream_t stream) {
    const float* x  = (const float*)d_in[0];
    const float* up = (const float*)d_in[1];
    float* out = (float*)d_out;

    const size_t MB32 = (size_t)64 * 512 * 512 * 2;   // one bf16 panel set
    if (ws_size >= 4 * MB32) {
        uint16_t* XB = (uint16_t*)d_ws;
        uint16_t* UB = XB + 16777216;
        uint16_t* UT = UB + 16777216;
        uint16_t* W  = UT + 16777216;
        kPrepUp3<<<512, 256, 0, stream>>>(up, x, UB, UT, XB);
        kGemmP<1><<<256, 512, 0, stream>>>(XB, UB, W);
        kGemmP<2><<<256, 512, 0, stream>>>(W, UT, out);
    } else {
        kNaive<<<512 * 64, 256, 0, stream>>>(x, up, out);
    }
}